// Round 1
// baseline (293.389 us; speedup 1.0000x reference)
//
#include <hip/hip_runtime.h>
#include <hip/hip_bf16.h>
#include <hip/hip_fp16.h>
#include <stdint.h>

typedef __attribute__((ext_vector_type(8))) short short8;
typedef __attribute__((ext_vector_type(16))) float f32x16;

#define DEVI __device__ __forceinline__

// pack two f32 -> two f16 in one u32 (lo = a, hi = b)
DEVI unsigned pkh(float a, float b){
  unsigned la = (unsigned)__half_as_ushort(__float2half(a));
  unsigned lb = (unsigned)__half_as_ushort(__float2half(b));
  return la | (lb << 16);
}

// barrier that drains LDS ops only (keeps prefetch global loads in flight)
DEVI void sync_lds(){
  asm volatile("s_waitcnt lgkmcnt(0)" ::: "memory");
  __builtin_amdgcn_s_barrier();
}

DEVI f32x16 zero16(){
  f32x16 z;
#pragma unroll
  for (int i = 0; i < 16; ++i) z[i] = 0.0f;
  return z;
}

#define TR_READ(dst, addr, IMM) \
  asm volatile("ds_read_b64_tr_b16 %0, %1 offset:" IMM : "=v"(dst) : "v"(addr))

// B=4 H=16 S=2048 D=128. grid = 64*16 blocks, 256 threads (4 waves x 32 q rows).
__global__ __launch_bounds__(256, 2)
void sdpa_fwd(const float* __restrict__ Qg, const float* __restrict__ Kg,
              const float* __restrict__ Vg, const int* __restrict__ Mg,
              float* __restrict__ Og)
{
  constexpr int S = 2048, D = 128;
  __shared__ __align__(16) short Klds[64*136];   // row-major [kv][d], pad 136
  __shared__ __align__(16) short Vlds[64*128];   // subtiled [kv/4][d/16][4][16] for tr_b16
  __shared__ __align__(16) float Mlds[64];

  const int tid  = threadIdx.x;
  const int lane = tid & 63;
  const int wv   = tid >> 6;
  const int h    = lane >> 5;         // k-group within mfma
  const int r31  = lane & 31;
  const int r15  = lane & 15;
  const int b4   = (lane >> 4) & 1;
  const int srow = tid >> 5;          // staging row 0..7
  const int scol = tid & 31;          // staging float4 col

  const int bh = blockIdx.x >> 4;
  const int qb = blockIdx.x & 15;

  const float* Qh = Qg + (size_t)bh * S * D;
  const float* Kh = Kg + (size_t)bh * S * D;
  const float* Vh = Vg + (size_t)bh * S * D;
  const int*   Mh = Mg + (size_t)bh * S;
  float*       Oh = Og + (size_t)bh * S * D;

  const int q0 = qb*128 + wv*32 + r31;   // this lane's q row

  // ---- Q fragments (f16, B-operand: lane holds Q[q0][16*df + 8*h + j]) ----
  short8 qs[8];
#pragma unroll
  for (int df = 0; df < 8; ++df){
    const float* p0 = Qh + (size_t)q0 * D + df*16 + h*8;
    float4 a = *(const float4*)(p0);
    float4 b = *(const float4*)(p0 + 4);
    union { unsigned u[4]; short8 s; } cv;
    cv.u[0] = pkh(a.x, a.y); cv.u[1] = pkh(a.z, a.w);
    cv.u[2] = pkh(b.x, b.y); cv.u[3] = pkh(b.z, b.w);
    qs[df] = cv.s;
  }

  // ---- prologue: load KV tile 0 into regs ----
  float4 kr[8], vr[8];
  int mpre = 1;
#pragma unroll
  for (int p = 0; p < 8; ++p){
    int row = p*8 + srow;
    kr[p] = *(const float4*)&Kh[(size_t)row * D + scol*4];
    vr[p] = *(const float4*)&Vh[(size_t)row * D + scol*4];
  }
  if (tid < 64) mpre = Mh[tid];

  f32x16 accO[4];
#pragma unroll
  for (int dn = 0; dn < 4; ++dn) accO[dn] = zero16();
  float mrun = -INFINITY, lrun = 0.0f;

  // per-lane byte address into V tile for tr reads
  const unsigned vbase = (unsigned)(size_t)(&Vlds[0])
                       + (unsigned)(h*2048 + b4*128 + r15*8);

  for (int t = 0; t < 32; ++t){
    // ---- stage tile t regs -> LDS (fp32 -> f16) ----
#pragma unroll
    for (int p = 0; p < 8; ++p){
      int row = p*8 + srow;
      unsigned k0 = pkh(kr[p].x, kr[p].y), k1 = pkh(kr[p].z, kr[p].w);
      *(unsigned long long*)&Klds[row*136 + scol*4] =
          ((unsigned long long)k1 << 32) | k0;
      unsigned v0 = pkh(vr[p].x, vr[p].y), v1 = pkh(vr[p].z, vr[p].w);
      int E = (row >> 2)*512 + (scol >> 2)*64 + (row & 3)*16 + (scol & 3)*4;
      *(unsigned long long*)&Vlds[E] =
          ((unsigned long long)v1 << 32) | v0;
    }
    if (tid < 64) Mlds[tid] = (mpre != 0) ? 1.0f : 0.0f;

    // ---- prefetch tile t+1 (flies under compute; WAR on kr/vr is safe) ----
    if (t < 31){
      const int kv0 = (t+1)*64;
#pragma unroll
      for (int p = 0; p < 8; ++p){
        int row = kv0 + p*8 + srow;
        kr[p] = *(const float4*)&Kh[(size_t)row * D + scol*4];
        vr[p] = *(const float4*)&Vh[(size_t)row * D + scol*4];
      }
      if (tid < 64) mpre = Mh[kv0 + tid];
    }

    sync_lds();

    // ---- QK^T (swapped): S^T[kv][q] = K * Q^T ----
    f32x16 sa[2];
    sa[0] = zero16(); sa[1] = zero16();
    __builtin_amdgcn_s_setprio(1);
#pragma unroll
    for (int mf = 0; mf < 2; ++mf){
#pragma unroll
      for (int df = 0; df < 8; ++df){
        short8 kf8 = *(const short8*)&Klds[(mf*32 + r31)*136 + df*16 + h*8];
        sa[mf] = __builtin_amdgcn_mfma_f32_32x32x16_f16(kf8, qs[df], sa[mf], 0, 0, 0);
      }
    }
    __builtin_amdgcn_s_setprio(0);

    // ---- online softmax (lane owns q col = r31; rows split across h) ----
    float pmax = -3.0e38f;
#pragma unroll
    for (int mf = 0; mf < 2; ++mf)
#pragma unroll
      for (int i = 0; i < 16; ++i) pmax = fmaxf(pmax, sa[mf][i]);
    pmax = fmaxf(pmax, __shfl_xor(pmax, 32, 64));
    const float mnew  = fmaxf(mrun, pmax);
    const float scale = __expf(mrun - mnew);
    float psum = 0.0f;
#pragma unroll
    for (int mf = 0; mf < 2; ++mf){
#pragma unroll
      for (int rb = 0; rb < 4; ++rb){
        float4 mv = *(const float4*)&Mlds[mf*32 + rb*8 + h*4];
        float mva[4] = {mv.x, mv.y, mv.z, mv.w};
#pragma unroll
        for (int i = 0; i < 4; ++i){
          float e = __expf(sa[mf][rb*4 + i] - mnew) * mva[i];
          sa[mf][rb*4 + i] = e;
          psum += e;
        }
      }
    }
    psum += __shfl_xor(psum, 32, 64);
    lrun = lrun * scale + psum;
    mrun = mnew;
#pragma unroll
    for (int dn = 0; dn < 4; ++dn)
#pragma unroll
      for (int i = 0; i < 16; ++i) accO[dn][i] *= scale;

    // ---- P fragments in-register (C-layout -> B-operand via shfl_xor 32) ----
    short8 pf8[4];
#pragma unroll
    for (int kf = 0; kf < 4; ++kf){
      const int mf = kf >> 1, o = (kf & 1)*8;
      unsigned w0 = pkh(sa[mf][o+0], sa[mf][o+1]);
      unsigned w1 = pkh(sa[mf][o+2], sa[mf][o+3]);
      unsigned w2 = pkh(sa[mf][o+4], sa[mf][o+5]);
      unsigned w3 = pkh(sa[mf][o+6], sa[mf][o+7]);
      unsigned sw0 = __shfl_xor(w0, 32, 64);
      unsigned sw1 = __shfl_xor(w1, 32, 64);
      unsigned sw2 = __shfl_xor(w2, 32, 64);
      unsigned sw3 = __shfl_xor(w3, 32, 64);
      union { unsigned u[4]; short8 s; } cv;
      cv.u[0] = h ? sw2 : w0;   // rows 16kf + {0,1 | 8,9}
      cv.u[1] = h ? sw3 : w1;   // rows 16kf + {2,3 | 10,11}
      cv.u[2] = h ? w2  : sw0;  // rows 16kf + {4,5 | 12,13}
      cv.u[3] = h ? w3  : sw1;  // rows 16kf + {6,7 | 14,15}
      pf8[kf] = cv.s;
    }

    // ---- PV: O^T[d][q] += V^T * P^T  (V^T A-frags via ds_read_b64_tr_b16) ----
#pragma unroll
    for (int dn = 0; dn < 4; ++dn){
      unsigned vdn = vbase + dn*256;
      unsigned long long ta0, ta1, tb0, tb1, tc0, tc1, td0, td1;
      TR_READ(ta0, vdn, "0");     TR_READ(ta1, vdn, "1024");
      TR_READ(tb0, vdn, "4096");  TR_READ(tb1, vdn, "5120");
      TR_READ(tc0, vdn, "8192");  TR_READ(tc1, vdn, "9216");
      TR_READ(td0, vdn, "12288"); TR_READ(td1, vdn, "13312");
      asm volatile("s_waitcnt lgkmcnt(0)" ::: "memory");
      __builtin_amdgcn_sched_barrier(0);
      union { unsigned long long q[2]; short8 s; } fa, fb, fc, fd;
      fa.q[0] = ta0; fa.q[1] = ta1;
      fb.q[0] = tb0; fb.q[1] = tb1;
      fc.q[0] = tc0; fc.q[1] = tc1;
      fd.q[0] = td0; fd.q[1] = td1;
      __builtin_amdgcn_s_setprio(1);
      accO[dn] = __builtin_amdgcn_mfma_f32_32x32x16_f16(fa.s, pf8[0], accO[dn], 0, 0, 0);
      accO[dn] = __builtin_amdgcn_mfma_f32_32x32x16_f16(fb.s, pf8[1], accO[dn], 0, 0, 0);
      accO[dn] = __builtin_amdgcn_mfma_f32_32x32x16_f16(fc.s, pf8[2], accO[dn], 0, 0, 0);
      accO[dn] = __builtin_amdgcn_mfma_f32_32x32x16_f16(fd.s, pf8[3], accO[dn], 0, 0, 0);
      __builtin_amdgcn_s_setprio(0);
    }

    sync_lds();
  }

  // ---- epilogue: O[q][d] = accO^T / l ----
  const float inv = 1.0f / lrun;
  float* Orow = Oh + (size_t)q0 * D;
#pragma unroll
  for (int dn = 0; dn < 4; ++dn){
#pragma unroll
    for (int rb = 0; rb < 4; ++rb){
      float4 o4;
      o4.x = accO[dn][rb*4+0]*inv;
      o4.y = accO[dn][rb*4+1]*inv;
      o4.z = accO[dn][rb*4+2]*inv;
      o4.w = accO[dn][rb*4+3]*inv;
      *(float4*)&Orow[dn*32 + rb*8 + h*4] = o4;
    }
  }
}

extern "C" void kernel_launch(void* const* d_in, const int* in_sizes, int n_in,
                              void* d_out, int out_size, void* d_ws, size_t ws_size,
                              hipStream_t stream) {
  const float* q = (const float*)d_in[0];
  const float* k = (const float*)d_in[1];
  const float* v = (const float*)d_in[2];
  const int*   m = (const int*)d_in[3];
  float* out = (float*)d_out;
  sdpa_fwd<<<dim3(64*16), dim3(256), 0, stream>>>(q, k, v, m, out);
}